// Round 4
// baseline (741797.998 us; speedup 1.0000x reference)
//
#include <hip/hip_runtime.h>
#include <math.h>

#define DN 2048
#define LEAF 16
#define NLEAVES 128
#define NB 64
#define EPSF 5.9604645e-08f      /* slamch('E') = 2^-24 */
#define SAFMINF 1.17549435e-38f

typedef float2 cplx;

struct Ctl {
  float orgnrm;
  int K;
  int ctot[4];
  float rho;
  int nrot;
  int n12, n23;
};

__device__ __forceinline__ cplx mkc(float x, float y){ cplx c; c.x=x; c.y=y; return c; }
__device__ __forceinline__ cplx cmul(cplx a, cplx b){ return mkc(a.x*b.x - a.y*b.y, a.x*b.y + a.y*b.x); }
__device__ __forceinline__ cplx cconj(cplx a){ return mkc(a.x, -a.y); }
__device__ __forceinline__ cplx cadd(cplx a, cplx b){ return mkc(a.x+b.x, a.y+b.y); }
__device__ __forceinline__ cplx cinv(cplx b){
  if (fabsf(b.x) >= fabsf(b.y)) { float r = b.y/b.x; float den = b.x + b.y*r; return mkc(1.f/den, -r/den); }
  else { float r = b.x/b.y; float den = b.x*r + b.y; return mkc(r/den, -1.f/den); }
}

/* ---------------- build H = i*(triu(sk,1) - triu(sk,1)^T), column-major ---------------- */
__global__ void k_buildH(const float* sk, cplx* AH){
  int idx = blockIdx.x*256 + threadIdx.x;
  if (idx >= DN*DN) return;
  int c = idx / DN, r = idx % DN;
  float im;
  if (r > c) im = -sk[(size_t)c*DN + r];
  else if (r < c) im = sk[(size_t)r*DN + c];
  else im = 0.f;
  AH[(size_t)c*DN + r] = mkc(copysignf(0.f, im), im);
}

/* ---------------- chetd2 (lower) step kernels ---------------- */
__global__ void k_clarfg(cplx* AH, cplx* tau, float* e, int j){
  __shared__ float red[256];
  __shared__ cplx ssc; __shared__ int sdo;
  int t = threadIdx.x;
  cplx* col = AH + (size_t)j*DN;
  float ssq = 0.f;
  for (int r = j+2+t; r < DN; r += 256){ cplx v = col[r]; ssq += v.x*v.x + v.y*v.y; }
  red[t]=ssq; __syncthreads();
  for (int s=128;s>0;s>>=1){ if (t<s) red[t]+=red[t+s]; __syncthreads(); }
  if (t==0){
    float xnorm = sqrtf(red[0]);
    cplx alpha = col[j+1];
    if (xnorm == 0.f && alpha.y == 0.f){
      tau[j] = mkc(0.f,0.f); e[j] = alpha.x; sdo = 0;
    } else {
      float beta = -copysignf(sqrtf(alpha.x*alpha.x + alpha.y*alpha.y + xnorm*xnorm), alpha.x);
      tau[j] = mkc((beta - alpha.x)/beta, -alpha.y/beta);
      ssc = cinv(mkc(alpha.x - beta, alpha.y));
      e[j] = beta;
      col[j+1] = mkc(beta, 0.f);
      sdo = 1;
    }
  }
  __syncthreads();
  if (sdo){ cplx sc = ssc; for (int r=j+2+t; r<DN; r+=256) col[r] = cmul(col[r], sc); }
}

__global__ void k_gemv(const cplx* AH, cplx* w, const cplx* tau, int j, int m){
  int i = blockIdx.x*blockDim.x + threadIdx.x;
  if (i >= m) return;
  const cplx* vcol = AH + (size_t)j*DN + (j+1);
  cplx acc = mkc(0.f,0.f);
  for (int c = 0; c < m; ++c){
    cplx a = AH[(size_t)(j+1+c)*DN + (j+1+i)];
    cplx v = (c==0)? mkc(1.f,0.f) : vcol[c];
    acc.x += a.x*v.x - a.y*v.y;
    acc.y += a.x*v.y + a.y*v.x;
  }
  w[i] = cmul(tau[j], acc);
}

__global__ void k_axpy(const cplx* AH, cplx* w, const cplx* tau, int j, int m){
  __shared__ float rx[256], ry[256];
  __shared__ cplx salpha;
  int t = threadIdx.x;
  const cplx* vcol = AH + (size_t)j*DN + (j+1);
  float dx=0.f, dy=0.f;
  for (int i=t; i<m; i+=256){
    cplx v = (i==0)? mkc(1.f,0.f) : vcol[i]; cplx ww = w[i];
    dx += ww.x*v.x + ww.y*v.y;      /* conj(w)*v */
    dy += ww.x*v.y - ww.y*v.x;
  }
  rx[t]=dx; ry[t]=dy; __syncthreads();
  for (int s=128;s>0;s>>=1){ if (t<s){ rx[t]+=rx[t+s]; ry[t]+=ry[t+s]; } __syncthreads(); }
  if (t==0){ cplx dot = mkc(rx[0], ry[0]); cplx a = cmul(tau[j], dot); salpha = mkc(-0.5f*a.x, -0.5f*a.y); }
  __syncthreads();
  cplx al = salpha;
  for (int i=t; i<m; i+=256){ cplx v = (i==0)? mkc(1.f,0.f) : vcol[i]; w[i] = cadd(w[i], cmul(al, v)); }
}

/* r on low lanes for coalesced writes */
__global__ void k_her2(cplx* AH, const cplx* w, int j, int m){
  int r = blockIdx.x*32 + (threadIdx.x & 31);
  int c = blockIdx.y*8 + (threadIdx.x >> 5);
  if (r >= m || c >= m) return;
  const cplx* vcol = AH + (size_t)j*DN + (j+1);
  cplx vr = (r==0)? mkc(1.f,0.f) : vcol[r];
  cplx vc = (c==0)? mkc(1.f,0.f) : vcol[c];
  cplx wr = w[r], wc = w[c];
  cplx u = cadd(cmul(vr, cconj(wc)), cmul(wr, cconj(vc)));
  size_t idx = (size_t)(j+1+c)*DN + (j+1+r);
  AH[idx].x -= u.x; AH[idx].y -= u.y;
}

__global__ void k_collectD(const cplx* AH, float* d){
  int i = blockIdx.x*256 + threadIdx.x;
  if (i < DN) d[i] = AH[(size_t)i*DN + i].x;
}

__global__ void k_zeroZ(float* Z){
  int idx = blockIdx.x*256 + threadIdx.x;
  if (idx < DN*DN) Z[idx] = 0.f;
}

/* ---------------- sstedc prep: norm, scale, tear, indxq ---------------- */
__global__ void k_predc(float* d, float* e, int* indxq, Ctl* ctl){
  __shared__ float red[256];
  int t = threadIdx.x;
  float mx = 0.f;
  for (int i=t;i<DN;i+=256) mx = fmaxf(mx, fabsf(d[i]));
  for (int i=t;i<DN-1;i+=256) mx = fmaxf(mx, fabsf(e[i]));
  red[t]=mx; __syncthreads();
  for (int s=128;s>0;s>>=1){ if (t<s) red[t]=fmaxf(red[t],red[t+s]); __syncthreads(); }
  float orgnrm = red[0];
  if (t==0) ctl->orgnrm = orgnrm;
  float mul = 1.f/orgnrm;
  __syncthreads();
  for (int i=t;i<DN;i+=256) d[i]*=mul;
  for (int i=t;i<DN-1;i+=256) e[i]*=mul;
  __syncthreads();
  if (t==0){
    for (int b=1;b<NLEAVES;b++){ int s0=b*LEAF; float ae=fabsf(e[s0-1]); d[s0-1]-=ae; d[s0]-=ae; }
  }
  for (int i=t;i<DN;i+=256) indxq[i] = (i & (LEAF-1)) + 1;
}

/* ---------------- ssteqr (small, serial) ---------------- */
__device__ void slaev2_d(float a, float b, float c, float* rt1, float* rt2, float* cs1, float* sn1){
  float sm = a + c, df = a - c, adf = fabsf(df), tb = b + b, ab = fabsf(tb);
  float acmx, acmn;
  if (fabsf(a) > fabsf(c)) { acmx = a; acmn = c; } else { acmx = c; acmn = a; }
  float rt;
  if (adf > ab) rt = adf*sqrtf(1.f + (ab/adf)*(ab/adf));
  else if (adf < ab) rt = ab*sqrtf(1.f + (adf/ab)*(adf/ab));
  else rt = ab*sqrtf(2.f);
  int sgn1;
  if (sm < 0.f){ *rt1 = 0.5f*(sm - rt); sgn1 = -1; *rt2 = (acmx/(*rt1))*acmn - (b/(*rt1))*b; }
  else if (sm > 0.f){ *rt1 = 0.5f*(sm + rt); sgn1 = 1; *rt2 = (acmx/(*rt1))*acmn - (b/(*rt1))*b; }
  else { *rt1 = 0.5f*rt; *rt2 = -0.5f*rt; sgn1 = 1; }
  float cs; int sgn2;
  if (df >= 0.f){ cs = df + rt; sgn2 = 1; } else { cs = df - rt; sgn2 = -1; }
  float acs = fabsf(cs);
  if (acs > ab){ float ct = -tb/cs; *sn1 = 1.f/sqrtf(1.f + ct*ct); *cs1 = ct*(*sn1); }
  else {
    if (ab == 0.f){ *cs1 = 1.f; *sn1 = 0.f; }
    else { float tn = -cs/tb; *cs1 = 1.f/sqrtf(1.f + tn*tn); *sn1 = tn*(*cs1); }
  }
  if (sgn1 == sgn2){ float tn = *cs1; *cs1 = -(*sn1); *sn1 = tn; }
}

/* LAPACK >=3.10 convention: c >= 0 always */
__device__ void slartg_d(float f, float g, float* cs, float* sn, float* r){
  if (g == 0.f){ *cs = 1.f; *sn = 0.f; *r = f; }
  else if (f == 0.f){ *cs = 0.f; *sn = copysignf(1.f, g); *r = fabsf(g); }
  else {
    float d = sqrtf(f*f + g*g);
    *cs = fabsf(f)/d;
    *r = copysignf(d, f);
    *sn = g/(*r);
  }
}

__device__ void rot1_d(float* z, int ldz, int nr, int col, float cc, float ss){
  for (int r=0;r<nr;++r){
    float tmp = z[(col+1)*ldz + r];
    z[(col+1)*ldz + r] = cc*tmp - ss*z[col*ldz + r];
    z[col*ldz + r] = ss*tmp + cc*z[col*ldz + r];
  }
}

__device__ void ssteqr_small(int n, float* d, float* e, float* z, int ldz){
  for (int c=0;c<n;c++) for (int r=0;r<n;r++) z[c*ldz+r] = (r==c)?1.f:0.f;
  const float eps=EPSF, eps2=eps*eps, safmin=SAFMINF;
  int nmaxit = n*30, jtot=0;
  int l1=0;
  float wc[LEAF], ws_[LEAF];
  while (1){
    if (l1 > n-1) break;
    if (l1 > 0) e[l1-1] = 0.f;
    int m;
    for (m = l1; m <= n-2; ++m){
      float tst = fabsf(e[m]);
      if (tst == 0.f) break;
      if (tst <= (sqrtf(fabsf(d[m]))*sqrtf(fabsf(d[m+1])))*eps){ e[m]=0.f; break; }
    }
    int l = l1, lend = m;
    l1 = m+1;
    if (lend == l) continue;
    if (fabsf(d[lend]) < fabsf(d[l])){ int tmp=l; l=lend; lend=tmp; }
    if (lend > l){
      /* QL */
      while (1){
        int mm;
        if (l != lend){
          for (mm = l; mm <= lend-1; ++mm){
            float tst = e[mm]*e[mm];
            if (tst <= (eps2*fabsf(d[mm]))*fabsf(d[mm+1]) + safmin) break;
          }
        } else mm = lend;
        if (mm < lend) e[mm] = 0.f;
        float p = d[l];
        if (mm == l){ d[l]=p; l++; if (l<=lend) continue; else break; }
        if (mm == l+1){
          float rt1, rt2, c_, s_;
          slaev2_d(d[l], e[l], d[l+1], &rt1, &rt2, &c_, &s_);
          rot1_d(z, ldz, n, l, c_, s_);
          d[l]=rt1; d[l+1]=rt2; e[l]=0.f;
          l += 2; if (l<=lend) continue; else break;
        }
        if (jtot == nmaxit) break;
        jtot++;
        float g = (d[l+1]-p)/(2.f*e[l]);
        float rr = sqrtf(g*g+1.f);
        g = d[mm] - p + e[l]/(g + copysignf(rr, g));
        float s_ = 1.f, c_ = 1.f; p = 0.f;
        for (int i = mm-1; i >= l; --i){
          float f = s_*e[i], b = c_*e[i];
          slartg_d(g, f, &c_, &s_, &rr);
          if (i != mm-1) e[i+1] = rr;
          g = d[i+1] - p;
          rr = (d[i]-g)*s_ + 2.f*c_*b;
          p = s_*rr;
          d[i+1] = g+p;
          g = c_*rr - b;
          wc[i] = c_; ws_[i] = -s_;
        }
        for (int q = mm-1; q >= l; --q) rot1_d(z, ldz, n, q, wc[q], ws_[q]);   /* 'B' */
        d[l] = d[l] - p; e[l] = g;
      }
    } else {
      /* QR */
      while (1){
        int mm;
        if (l != lend){
          for (mm = l; mm >= lend+1; --mm){
            float tst = e[mm-1]*e[mm-1];
            if (tst <= (eps2*fabsf(d[mm]))*fabsf(d[mm-1]) + safmin) break;
          }
        } else mm = lend;
        if (mm > lend) e[mm-1] = 0.f;
        float p = d[l];
        if (mm == l){ d[l]=p; l--; if (l>=lend) continue; else break; }
        if (mm == l-1){
          float rt1, rt2, c_, s_;
          slaev2_d(d[l-1], e[l-1], d[l], &rt1, &rt2, &c_, &s_);
          rot1_d(z, ldz, n, l-1, c_, s_);
          d[l-1]=rt1; d[l]=rt2; e[l-1]=0.f;
          l -= 2; if (l>=lend) continue; else break;
        }
        if (jtot == nmaxit) break;
        jtot++;
        float g = (d[l-1]-p)/(2.f*e[l-1]);
        float rr = sqrtf(g*g+1.f);
        g = d[mm] - p + e[l-1]/(g + copysignf(rr, g));
        float s_=1.f, c_=1.f; p=0.f;
        for (int i = mm; i <= l-1; ++i){
          float f = s_*e[i], b = c_*e[i];
          slartg_d(g, f, &c_, &s_, &rr);
          if (i != mm) e[i-1] = rr;
          g = d[i] - p;
          rr = (d[i+1]-g)*s_ + 2.f*c_*b;
          p = s_*rr;
          d[i] = g+p;
          g = c_*rr - b;
          wc[i] = c_; ws_[i] = s_;
        }
        for (int q = mm; q <= l-1; ++q) rot1_d(z, ldz, n, q, wc[q], ws_[q]);  /* 'F' */
        d[l] = d[l]-p; e[l-1] = g;
      }
    }
  }
  /* selection sort ascending + column swap */
  for (int ii=1; ii<n; ++ii){
    int i = ii-1, k = i; float pp = d[i];
    for (int jj=ii; jj<n; ++jj) if (d[jj] < pp){ k=jj; pp=d[jj]; }
    if (k != i){
      d[k]=d[i]; d[i]=pp;
      for (int r=0;r<n;r++){ float tv=z[i*ldz+r]; z[i*ldz+r]=z[k*ldz+r]; z[k*ldz+r]=tv; }
    }
  }
}

__global__ void k_leaves(float* d, float* e, float* Zmat){
  __shared__ float sd[LEAF], se[LEAF], sz[LEAF*LEAF];
  int off = blockIdx.x*LEAF;
  int t = threadIdx.x;
  if (t < LEAF){ sd[t] = d[off+t]; se[t] = (t<LEAF-1)? e[off+t] : 0.f; }
  __syncthreads();
  if (t==0) ssteqr_small(LEAF, sd, se, sz, LEAF);
  __syncthreads();
  if (t < LEAF){ d[off+t]=sd[t]; if (t<LEAF-1) e[off+t]=se[t]; }
  for (int i=t; i<LEAF*LEAF; i+=64){
    int c = i/LEAF, r = i%LEAF;
    Zmat[(size_t)(off+c)*DN + (off+r)] = sz[c*LEAF+r];
  }
}

/* ---------------- merge: slaed1/slaed2 prep (serial core on thread 0) ---------------- */
__global__ void k_mprep(float* d, const float* e, const float* Zmat, int* indxq,
                        float* z, float* dtmp, float* dlamda, float* wkeep,
                        int* indx, int* indxc, int* indxp, int* coltyp,
                        float* rotc, float* rots, int* rotp, int* rotn,
                        Ctl* ctl, int off, int n, int n1)
{
  __shared__ float red[256];
  int t = threadIdx.x; int n2 = n - n1;
  float rho0 = e[off + n1 - 1];
  for (int c = t; c < n; c += 256){
    float val = (c < n1) ? Zmat[(size_t)(off+c)*DN + (off+n1-1)]
                         : Zmat[(size_t)(off+c)*DN + (off+n1)];
    if (c >= n1){ if (rho0 < 0.f) val = -val; indxq[off+c] += n1; }
    z[c] = val * 0.70710678118654752440f;
  }
  __syncthreads();
  for (int i = t; i < n; i += 256) dtmp[i] = d[off + indxq[off+i] - 1];
  __syncthreads();
  if (t == 0){
    int i1=0, i2=n1, ns1=n1, ns2=n2, k=0;
    while (ns1>0 && ns2>0){
      if (dtmp[i1] <= dtmp[i2]){ indxc[k++]=i1+1; i1++; ns1--; }
      else { indxc[k++]=i2+1; i2++; ns2--; }
    }
    while (ns1>0){ indxc[k++]=i1+1; i1++; ns1--; }
    while (ns2>0){ indxc[k++]=i2+1; i2++; ns2--; }
  }
  __syncthreads();
  /* NOTE: indx is stored 0-BASED (indxq values are 1-based) */
  for (int i = t; i < n; i += 256) indx[i] = indxq[off + indxc[i] - 1] - 1;
  __syncthreads();
  float mz=0.f, md=0.f;
  for (int i=t;i<n;i+=256){ mz = fmaxf(mz, fabsf(z[i])); md = fmaxf(md, fabsf(d[off+i])); }
  red[t]=mz; __syncthreads();
  for (int s=128;s>0;s>>=1){ if (t<s) red[t]=fmaxf(red[t],red[t+s]); __syncthreads(); }
  mz = red[0]; __syncthreads();
  red[t]=md; __syncthreads();
  for (int s=128;s>0;s>>=1){ if (t<s) red[t]=fmaxf(red[t],red[t+s]); __syncthreads(); }
  md = red[0];
  if (t == 0){
    float rho = fabsf(2.f*rho0);
    float tol = 8.f*EPSF*fmaxf(md, mz);
    ctl->rho = rho;
    if (rho*mz <= tol){
      /* all deflated: indx (sorted order) drives the copy kernels */
      ctl->K = 0; ctl->nrot = 0;
      ctl->ctot[0]=0; ctl->ctot[1]=0; ctl->ctot[2]=0; ctl->ctot[3]=n;
      ctl->n12 = 0; ctl->n23 = 0;
    } else {
      for (int i=0;i<n1;i++) coltyp[i]=0;
      for (int i=n1;i<n;i++) coltyp[i]=2;
      int K=0, k2=n, nrot=0, pj=0;
      int jj=0;
      for (; jj<n; ++jj){
        int nj = indx[jj];
        if (rho*fabsf(z[nj]) <= tol){ k2--; coltyp[nj]=3; indxp[k2]=nj; }
        else { pj = nj; break; }
      }
      for (;;){
        jj++;
        if (jj >= n) break;
        int nj = indx[jj];
        if (rho*fabsf(z[nj]) <= tol){ k2--; coltyp[nj]=3; indxp[k2]=nj; }
        else {
          float s_ = z[pj], c_ = z[nj];
          float tau_ = sqrtf(c_*c_ + s_*s_);
          float tt = d[off+nj] - d[off+pj];
          c_ = c_/tau_; s_ = -s_/tau_;
          if (fabsf(tt*c_*s_) <= tol){
            z[nj] = tau_; z[pj] = 0.f;
            if (coltyp[nj] != coltyp[pj]) coltyp[nj] = 1;
            coltyp[pj] = 3;
            rotp[nrot]=pj; rotn[nrot]=nj; rotc[nrot]=c_; rots[nrot]=s_; nrot++;
            float t2 = d[off+pj]*c_*c_ + d[off+nj]*s_*s_;
            d[off+nj] = d[off+pj]*s_*s_ + d[off+nj]*c_*c_;
            d[off+pj] = t2;
            k2--;
            int ii = 1;
            for (;;){
              if (k2+ii <= n-1){
                if (d[off+pj] < d[off+indxp[k2+ii]]){ indxp[k2+ii-1]=indxp[k2+ii]; indxp[k2+ii]=pj; ii++; }
                else { indxp[k2+ii-1]=pj; break; }
              } else { indxp[k2+ii-1]=pj; break; }
            }
            pj = nj;
          } else {
            dlamda[K]=d[off+pj]; wkeep[K]=z[pj]; indxp[K]=pj; K++;
            pj = nj;
          }
        }
      }
      dlamda[K]=d[off+pj]; wkeep[K]=z[pj]; indxp[K]=pj; K++;
      int ct[4]={0,0,0,0};
      for (int q=0;q<n;q++) ct[coltyp[q]]++;
      int psm[4]; psm[0]=0; psm[1]=ct[0]; psm[2]=ct[0]+ct[1]; psm[3]=ct[0]+ct[1]+ct[2];
      for (int q=0;q<n;q++){
        int js = indxp[q]; int cc = coltyp[js];
        indx[psm[cc]] = js; indxc[psm[cc]] = q; psm[cc]++;
      }
      ctl->K = K; ctl->nrot = nrot;
      ctl->ctot[0]=ct[0]; ctl->ctot[1]=ct[1]; ctl->ctot[2]=ct[2]; ctl->ctot[3]=ct[3];
      ctl->n12 = ct[0]+ct[1]; ctl->n23 = ct[1]+ct[2];
    }
  }
}

__global__ void k_mrot(float* Zmat, const float* rotc, const float* rots,
                       const int* rotp, const int* rotn, const Ctl* ctl, int off, int n){
  int r = blockIdx.x*256 + threadIdx.x;
  if (r >= n) return;
  int nrot = ctl->nrot;
  for (int q=0;q<nrot;++q){
    size_t ip = (size_t)(off+rotp[q])*DN + off + r;
    size_t in_ = (size_t)(off+rotn[q])*DN + off + r;
    float x = Zmat[ip], y = Zmat[in_];
    float cc = rotc[q], ss = rots[q];
    Zmat[ip]  = cc*x + ss*y;
    Zmat[in_] = cc*y - ss*x;
  }
}

__global__ void k_mcopyA(const float* d, const float* Zmat, float* Q2, float* dgrp,
                         const int* indx, const Ctl* ctl, int off, int n, int n1){
  int p = blockIdx.x; if (p >= n) return;
  int t = threadIdx.x; int n2 = n - n1;
  int c0 = ctl->ctot[0], c1 = ctl->ctot[1], c2 = ctl->ctot[2];
  int K = c0+c1+c2;
  int src = indx[p];
  const float* qcol = Zmat + (size_t)(off+src)*DN + off;
  if (t == 0) dgrp[p] = d[off+src];
  size_t base2 = (size_t)n1*(c0+c1);
  size_t base3 = base2 + (size_t)n2*(c1+c2);
  if (p < c0){
    float* dst = Q2 + (size_t)p*n1;
    for (int r=t;r<n1;r+=256) dst[r] = qcol[r];
  } else if (p < c0+c1){
    float* d1 = Q2 + (size_t)p*n1;
    float* d2 = Q2 + base2 + (size_t)(p-c0)*n2;
    for (int r=t;r<n1;r+=256) d1[r] = qcol[r];
    for (int r=t;r<n2;r+=256) d2[r] = qcol[n1+r];
  } else if (p < K){
    float* d2 = Q2 + base2 + (size_t)(p-c0)*n2;
    for (int r=t;r<n2;r+=256) d2[r] = qcol[n1+r];
  } else {
    float* dst = Q2 + base3 + (size_t)(p-K)*n;
    for (int r=t;r<n;r+=256) dst[r] = qcol[r];
  }
}

__global__ void k_mcopyB(float* d, float* Zmat, const float* Q2, const float* dgrp,
                         const Ctl* ctl, int off, int n, int n1){
  int p = blockIdx.x; if (p >= n) return;
  int t = threadIdx.x; int n2 = n - n1;
  int c0 = ctl->ctot[0], c1 = ctl->ctot[1], c2 = ctl->ctot[2];
  int K = c0+c1+c2;
  if (p < K) return;
  size_t base3 = (size_t)n1*(c0+c1) + (size_t)n2*(c1+c2);
  const float* src = Q2 + base3 + (size_t)(p-K)*n;
  float* dst = Zmat + (size_t)(off+p)*DN + off;
  for (int r=t;r<n;r+=256) dst[r] = src[r];
  if (t==0) d[off+p] = dgrp[p];
}

/* ---------------- secular equation solver (slaed4-style, shifted coordinates) ---------------- */
__global__ void k_msec(float* d, float* Zmat, const float* dl, const float* w,
                       const Ctl* ctl, int off){
  int j = blockIdx.x*64 + threadIdx.x;
  int K = ctl->K;
  if (j >= K) return;
  float rho = ctl->rho;
  float* delta = Zmat + (size_t)(off+j)*DN + off;
  if (K == 1){
    d[off] = dl[0] + rho*w[0]*w[0];
    delta[0] = 1.f;
    return;
  }
  int orig; float lo, hi;
  if (j < K-1){
    float gap = dl[j+1] - dl[j];
    float half = 0.5f*gap;
    /* secular f at the midpoint, evaluated in shifted coords (no pole hit possible) */
    float fmid = 1.f;
    for (int l=0;l<K;l++){
      float D = (dl[l]-dl[j]) - half;
      fmid += rho*w[l]*w[l]/D;
    }
    if (fmid >= 0.f){ orig = j;   lo = 0.f;   hi = half; }
    else            { orig = j+1; lo = -half; hi = 0.f;  }
  } else {
    float s2 = 0.f;
    for (int l=0;l<K;l++) s2 += w[l]*w[l];
    orig = K-1; lo = 0.f; hi = rho*s2*1.000002f + 1e-30f;
  }
  float dorig = dl[orig];
  float eta = 0.5f*(lo+hi);
  for (int it=0; it<50; ++it){
    float g = 1.f, gp = 0.f;
    for (int l=0;l<K;l++){
      float del = (dl[l]-dorig) - eta;
      float r = w[l]/del;
      g  += rho*w[l]*r;
      gp += rho*r*r;
    }
    if (g > 0.f) hi = eta; else lo = eta;
    float etan = eta - g/gp;
    if (!(etan > lo && etan < hi)) etan = 0.5f*(lo+hi);
    if (etan == eta) break;
    eta = etan;
  }
  d[off+j] = dorig + eta;
  for (int l=0;l<K;l++) delta[l] = (dl[l]-dorig) - eta;
}

__global__ void k_mzhat(const float* dlamda, const float* wkeep, float* what,
                        const float* Zmat, const Ctl* ctl, int off){
  int K = ctl->K;
  int i = blockIdx.x*64 + threadIdx.x;
  if (i >= K) return;
  float acc = Zmat[(size_t)(off+i)*DN + off+i];
  float di = dlamda[i];
  for (int jj=0;jj<K;jj++){
    if (jj==i) continue;
    acc *= Zmat[(size_t)(off+jj)*DN + off+i] / (di - dlamda[jj]);
  }
  what[i] = copysignf(sqrtf(fabsf(acc)), wkeep[i]);
}

__global__ void k_mvec(float* Zmat, const float* what, const int* indxc,
                       const Ctl* ctl, int off){
  __shared__ float sv[2048];
  __shared__ float red[256];
  int K = ctl->K; int j = blockIdx.x;
  if (j >= K) return;
  int t = threadIdx.x;
  float* col = Zmat + (size_t)(off+j)*DN + off;
  float ssq = 0.f;
  for (int i=t;i<K;i+=256){
    float den = col[i];
    if (den == 0.f) den = 1e-30f;   /* defensive: cannot happen per slaed4 bracket */
    float v = what[i]/den; sv[i]=v; ssq += v*v;
  }
  red[t]=ssq; __syncthreads();
  for (int s=128;s>0;s>>=1){ if (t<s) red[t]+=red[t+s]; __syncthreads(); }
  float temp = sqrtf(red[0]);
  for (int i=t;i<K;i+=256) col[i] = sv[indxc[i]]/temp;
}

__global__ void k_mcopyS(float* Smat, const float* Zmat, const Ctl* ctl, int off, int mode){
  int K = ctl->K; if (K==0) return;
  int rows = (mode==1)? ctl->n23 : ctl->n12;
  int rowoff = (mode==1)? ctl->ctot[0] : 0;
  if (rows==0) return;
  size_t tot = (size_t)rows*K;
  for (size_t idx = (size_t)blockIdx.x*256+threadIdx.x; idx < tot; idx += (size_t)gridDim.x*256){
    int r = (int)(idx % rows); int c = (int)(idx / rows);
    Smat[idx] = Zmat[(size_t)(off+c)*DN + off + rowoff + r];
  }
}

__global__ void k_sgemm_dc(float* Zmat, const float* Q2, const float* Smat,
                           const Ctl* ctl, int off, int n, int n1, int mode){
  int K = ctl->K; if (K==0) return;
  int n2 = n-n1;
  int m, kk; const float* A; int lda; float* C;
  if (mode==1){ m=n2; kk=ctl->n23; A = Q2 + (size_t)n1*ctl->n12; lda=n2; C = Zmat + (size_t)off*DN + off+n1; }
  else { m=n1; kk=ctl->n12; A = Q2; lda=n1; C = Zmat + (size_t)off*DN + off; }
  const float* B = Smat; int ldb = kk;
  int tr = blockIdx.x*32, tc = blockIdx.y*32;
  if (tr >= m || tc >= K) return;
  __shared__ float As[32][33], Bs[32][33];
  int tx = threadIdx.x & 31, ty = threadIdx.x >> 5;
  float acc[4] = {0.f,0.f,0.f,0.f};
  for (int k0=0;k0<kk;k0+=32){
    for (int q=0;q<4;q++){ int kc=k0+ty+q*8; int r=tr+tx;
      As[tx][ty+q*8] = (r<m && kc<kk)? A[(size_t)kc*lda + r] : 0.f; }
    for (int q=0;q<4;q++){ int cc=tc+ty+q*8; int kr=k0+tx;
      Bs[tx][ty+q*8] = (kr<kk && cc<K)? B[(size_t)cc*ldb + kr] : 0.f; }
    __syncthreads();
    for (int kq=0;kq<32;kq++){
      float a = As[tx][kq];
      #pragma unroll
      for (int q=0;q<4;q++) acc[q] += a*Bs[kq][ty+q*8];
    }
    __syncthreads();
  }
  int r = tr+tx;
  if (r < m){
    for (int q=0;q<4;q++){ int c = tc+ty+q*8; if (c < K) C[(size_t)c*DN + r] = acc[q]; }
  }
}

__global__ void k_mmerge(float* d, int* indxq, const Ctl* ctl, int off, int n){
  int K = ctl->K;
  if (K == 0){ for (int i=0;i<n;i++) indxq[off+i]=i+1; return; }
  int i1=0, i2=n-1, ns1=K, ns2=n-K, k=0;
  while (ns1>0 && ns2>0){
    if (d[off+i1] <= d[off+i2]){ indxq[off+k++]=i1+1; i1++; ns1--; }
    else { indxq[off+k++]=i2+1; i2--; ns2--; }
  }
  while (ns1>0){ indxq[off+k++]=i1+1; i1++; ns1--; }
  while (ns2>0){ indxq[off+k++]=i2+1; i2--; ns2--; }
}

/* ---------------- final permutation + scale back ---------------- */
__global__ void k_fpermA(const float* d, const float* Zmat, float* Q2, float* dtmp, const int* indxq){
  int i = blockIdx.x; int t = threadIdx.x;
  int src = indxq[i]-1;
  if (t==0) dtmp[i] = d[src];
  const float* sc = Zmat + (size_t)src*DN;
  float* dc = Q2 + (size_t)i*DN;
  for (int r=t;r<DN;r+=256) dc[r]=sc[r];
}
__global__ void k_fpermB(float* evals, float* Zmat, const float* Q2, const float* dtmp, const Ctl* ctl){
  int i = blockIdx.x; int t = threadIdx.x;
  if (t==0) evals[i] = dtmp[i]*ctl->orgnrm;
  const float* sc = Q2 + (size_t)i*DN;
  float* dc = Zmat + (size_t)i*DN;
  for (int r=t;r<DN;r+=256) dc[r]=sc[r];
}

/* ---------------- cunmqr (blocked, left, no-transpose) on split re/im planes ---------------- */
__global__ void k_packV(const cplx* AH, cplx* Vp, int i0, int ib, int m){
  int idx = blockIdx.x*256 + threadIdx.x;
  if (idx >= m*ib) return;
  int r = idx % m, c = idx / m;
  int grow = i0+1+r, pc = i0+c+1;
  cplx v;
  if (grow < pc) v = mkc(0.f,0.f);
  else if (grow == pc) v = mkc(1.f,0.f);
  else v = AH[(size_t)(i0+c)*DN + grow];
  Vp[(size_t)c*m + r] = v;
}

__global__ void k_vhv(const cplx* Vp, cplx* vhv, int m, int ib){
  __shared__ float rx[256], ry[256];
  int c = blockIdx.x; if (c >= ib) return;
  int t = threadIdx.x;
  for (int r=0; r<c; ++r){
    float dx=0.f, dy=0.f;
    for (int rl=c+t; rl<m; rl+=256){
      cplx a = Vp[(size_t)r*m + rl];
      cplx b = Vp[(size_t)c*m + rl];
      dx += a.x*b.x + a.y*b.y;     /* conj(a)*b */
      dy += a.x*b.y - a.y*b.x;
    }
    rx[t]=dx; ry[t]=dy; __syncthreads();
    for (int s=128;s>0;s>>=1){ if (t<s){ rx[t]+=rx[t+s]; ry[t]+=ry[t+s]; } __syncthreads(); }
    if (t==0) vhv[r + c*NB] = mkc(rx[0], ry[0]);
    __syncthreads();
  }
}

__global__ void k_bldT(const cplx* vhv, const cplx* tau, cplx* T, int ib){
  int t = threadIdx.x;
  for (int idx=t; idx<NB*NB; idx+=64) T[idx] = mkc(0.f,0.f);
  __syncthreads();
  for (int c=0; c<ib; ++c){
    if (t < c){
      cplx acc = mkc(0.f,0.f);
      for (int q=t; q<c; ++q) acc = cadd(acc, cmul(T[t + q*NB], vhv[q + c*NB]));
      cplx nt = mkc(-tau[c].x, -tau[c].y);
      T[t + c*NB] = cmul(nt, acc);
    }
    if (t == c) T[c + c*NB] = tau[c];
    __syncthreads();
  }
}

/* G1(ib x DN) = Vp^H (m x ib) * C(planes, rows row0..row0+m) */
__global__ void k_cgemm_ct_p(const cplx* A, const float* Cre, const float* Cim,
                             cplx* G1, int row0, int m, int ib){
  __shared__ cplx As[32][33], Bs[32][33];
  int tr = blockIdx.x*32, tc = blockIdx.y*32;
  if (tr >= ib) return;
  int tx = threadIdx.x & 31, ty = threadIdx.x >> 5;
  cplx acc[4]; for (int q=0;q<4;q++) acc[q]=mkc(0.f,0.f);
  for (int k0=0;k0<m;k0+=32){
    for (int q=0;q<4;q++){ int rr=tr+ty+q*8; int kr=k0+tx;
      As[tx][ty+q*8] = (kr<m && rr<ib)? cconj(A[(size_t)rr*m + kr]) : mkc(0.f,0.f); }
    for (int q=0;q<4;q++){ int cc=tc+ty+q*8; int kr=k0+tx;
      if (kr<m && cc<DN){ size_t bi = (size_t)cc*DN + row0 + kr; Bs[tx][ty+q*8] = mkc(Cre[bi], Cim[bi]); }
      else Bs[tx][ty+q*8] = mkc(0.f,0.f); }
    __syncthreads();
    for (int kq=0;kq<32;kq++){
      cplx a = As[kq][tx];
      #pragma unroll
      for (int q=0;q<4;q++){
        cplx b = Bs[kq][ty+q*8];
        acc[q].x += a.x*b.x - a.y*b.y;
        acc[q].y += a.x*b.y + a.y*b.x;
      }
    }
    __syncthreads();
  }
  int r = tr+tx;
  if (r < ib){
    for (int q=0;q<4;q++){ int c=tc+ty+q*8; if (c<DN) G1[r + (size_t)c*NB] = acc[q]; }
  }
}

/* G2 = Tm * G1 (both small, interleaved) */
__global__ void k_cgemm_nn(const cplx* A, int lda, const cplx* B, int ldb,
                           cplx* C, int ldc, int m, int nn, int kk){
  __shared__ cplx As[32][33], Bs[32][33];
  int tr = blockIdx.x*32, tc = blockIdx.y*32;
  if (tr >= m || tc >= nn) return;
  int tx = threadIdx.x & 31, ty = threadIdx.x >> 5;
  cplx acc[4]; for (int q=0;q<4;q++) acc[q]=mkc(0.f,0.f);
  for (int k0=0;k0<kk;k0+=32){
    for (int q=0;q<4;q++){ int kc=k0+ty+q*8; int r=tr+tx;
      As[tx][ty+q*8] = (r<m && kc<kk)? A[(size_t)kc*lda + r] : mkc(0.f,0.f); }
    for (int q=0;q<4;q++){ int cc=tc+ty+q*8; int kr=k0+tx;
      Bs[tx][ty+q*8] = (kr<kk && cc<nn)? B[(size_t)cc*ldb + kr] : mkc(0.f,0.f); }
    __syncthreads();
    for (int kq=0;kq<32;kq++){
      cplx a = As[tx][kq];
      #pragma unroll
      for (int q=0;q<4;q++){
        cplx b = Bs[kq][ty+q*8];
        acc[q].x += a.x*b.x - a.y*b.y;
        acc[q].y += a.x*b.y + a.y*b.x;
      }
    }
    __syncthreads();
  }
  int r = tr+tx;
  if (r < m){
    for (int q=0;q<4;q++){ int c = tc+ty+q*8; if (c < nn) C[r + (size_t)c*NB] = acc[q]; }
  }
}

/* C(planes, rows row0..) -= Vp(m x ib) * G2(ib x DN, ld NB) */
__global__ void k_cupdate_p(const cplx* A, const cplx* G2, float* Cre, float* Cim,
                            int row0, int m, int ib){
  __shared__ cplx As[32][33], Bs[32][33];
  int tr = blockIdx.x*32, tc = blockIdx.y*32;
  if (tr >= m) return;
  int tx = threadIdx.x & 31, ty = threadIdx.x >> 5;
  cplx acc[4]; for (int q=0;q<4;q++) acc[q]=mkc(0.f,0.f);
  for (int k0=0;k0<ib;k0+=32){
    for (int q=0;q<4;q++){ int kc=k0+ty+q*8; int r=tr+tx;
      As[tx][ty+q*8] = (r<m && kc<ib)? A[(size_t)kc*m + r] : mkc(0.f,0.f); }
    for (int q=0;q<4;q++){ int cc=tc+ty+q*8; int kr=k0+tx;
      Bs[tx][ty+q*8] = (kr<ib && cc<DN)? G2[kr + (size_t)cc*NB] : mkc(0.f,0.f); }
    __syncthreads();
    for (int kq=0;kq<32;kq++){
      cplx a = As[tx][kq];
      #pragma unroll
      for (int q=0;q<4;q++){
        cplx b = Bs[kq][ty+q*8];
        acc[q].x += a.x*b.x - a.y*b.y;
        acc[q].y += a.x*b.y + a.y*b.x;
      }
    }
    __syncthreads();
  }
  int r = tr+tx;
  if (r < m){
    for (int q=0;q<4;q++){
      int c = tc+ty+q*8;
      if (c < DN){
        size_t idx = (size_t)c*DN + row0 + r;
        Cre[idx] -= acc[q].x;
        Cim[idx] -= acc[q].y;
      }
    }
  }
}

/* ---------------- outputs (real parts only) ---------------- */
__global__ void k_outVre(const float* Cre, float* out0){
  int idx = blockIdx.x*256 + threadIdx.x;
  if (idx >= DN*DN) return;
  int r = idx >> 11, c = idx & (DN-1);
  out0[idx] = Cre[(size_t)c*DN + r];           /* Re V, row-major */
}
__global__ void k_outVinv(const float* Cre, float* out1){
  int idx = blockIdx.x*256 + threadIdx.x;
  if (idx >= DN*DN) return;
  out1[idx] = Cre[idx];                         /* Re V^H row-major == Cre col-major linear */
}
__global__ void k_outEvo(const float* evals, const float* dt, float* out2, int T){
  int idx = blockIdx.x*256 + threadIdx.x;
  if (idx >= T*DN) return;
  int k = idx & (DN-1), tt = idx >> 11;
  out2[idx] = cosf(evals[k]*dt[tt]);            /* Re exp(-i*lambda*dt) */
}

/* ---------------- host ---------------- */
extern "C" void kernel_launch(void* const* d_in, const int* in_sizes, int n_in,
                              void* d_out, int out_size, void* d_ws, size_t ws_size,
                              hipStream_t stream)
{
  const float* sk = (const float*)d_in[0];
  const float* dt = (const float*)d_in[1];
  int Ttot = in_sizes[1];
  float* out = (float*)d_out;
  (void)ws_size; (void)n_in; (void)out_size;

  /* d_out = 3*N^2 floats (real parts only):
     [0, 2N^2)    : AH (cplx, chetrd matrix + reflectors) -> Re(V) [0,N^2) + Re(Vinv) [N^2,2N^2) at end
     [2N^2, 3N^2) : Smat during D&C -> Re(evo) output
     d_ws:
     [0, N^2)     : Zmat (D&C eigvecs) == Cre (cunmqr real plane)
     [N^2, 2N^2)  : Q2 (D&C scratch)  == Cim (cunmqr imag plane)
     [2N^2, ...)  : small vectors + cunmqr block scratch (~4 MB) */
  const size_t N2 = (size_t)DN*DN;
  cplx*  AH   = (cplx*)out;
  float* Smat = out + 2*N2;
  float* Zmat = (float*)d_ws;           /* = Cre */
  float* Q2   = (float*)d_ws + N2;      /* = Cim */
  float* Cre  = Zmat;
  float* Cim  = Q2;

  char* wp = (char*)d_ws + 2*N2*sizeof(float);
  auto carve = [&](size_t b)->void*{ void* p=(void*)wp; wp += (b+255)&~(size_t)255; return p; };
  float* dd     = (float*)carve(DN*sizeof(float));
  float* ee     = (float*)carve(DN*sizeof(float));
  float* zz     = (float*)carve(DN*sizeof(float));
  float* dtmp   = (float*)carve(DN*sizeof(float));
  float* dlamda = (float*)carve(DN*sizeof(float));
  float* wkeep  = (float*)carve(DN*sizeof(float));
  float* what   = (float*)carve(DN*sizeof(float));
  float* dgrp   = (float*)carve(DN*sizeof(float));
  float* rotc   = (float*)carve(DN*sizeof(float));
  float* rots   = (float*)carve(DN*sizeof(float));
  float* evals  = (float*)carve(DN*sizeof(float));
  cplx*  tauA   = (cplx*)carve(DN*sizeof(cplx));
  cplx*  wvec   = (cplx*)carve(DN*sizeof(cplx));
  int*   indxq  = (int*)carve(DN*sizeof(int));
  int*   indx   = (int*)carve(DN*sizeof(int));
  int*   indxc  = (int*)carve(DN*sizeof(int));
  int*   indxp  = (int*)carve(DN*sizeof(int));
  int*   coltyp = (int*)carve(DN*sizeof(int));
  int*   rotp   = (int*)carve(DN*sizeof(int));
  int*   rotn   = (int*)carve(DN*sizeof(int));
  Ctl*   ctl    = (Ctl*)carve(sizeof(Ctl));
  cplx*  Vp     = (cplx*)carve((size_t)DN*NB*sizeof(cplx));
  cplx*  G1     = (cplx*)carve((size_t)NB*DN*sizeof(cplx));
  cplx*  G2     = (cplx*)carve((size_t)NB*DN*sizeof(cplx));
  cplx*  Tm     = (cplx*)carve((size_t)NB*NB*sizeof(cplx));
  cplx*  vhv    = (cplx*)carve((size_t)NB*NB*sizeof(cplx));

  /* 1. build H */
  k_buildH<<<(DN*DN+255)/256,256,0,stream>>>(sk, AH);

  /* 2. chetd2 lower (unblocked) */
  for (int j=0; j<=DN-2; ++j){
    int m = DN-1-j;
    k_clarfg<<<1,256,0,stream>>>(AH, tauA, ee, j);
    k_gemv<<<(m+255)/256,256,0,stream>>>(AH, wvec, tauA, j, m);
    k_axpy<<<1,256,0,stream>>>(AH, wvec, tauA, j, m);
    dim3 g2((m+31)/32,(m+7)/8);
    k_her2<<<g2,256,0,stream>>>(AH, wvec, j, m);
  }
  k_collectD<<<(DN+255)/256,256,0,stream>>>(AH, dd);

  /* 3. sstedc('I') equivalent (real D&C) */
  k_zeroZ<<<(DN*DN+255)/256,256,0,stream>>>(Zmat);
  k_predc<<<1,256,0,stream>>>(dd, ee, indxq, ctl);
  k_leaves<<<NLEAVES,64,0,stream>>>(dd, ee, Zmat);

  for (int sz = LEAF; sz < DN; sz *= 2){
    for (int off = 0; off < DN; off += 2*sz){
      int n = 2*sz, n1 = sz;
      k_mprep<<<1,256,0,stream>>>(dd, ee, Zmat, indxq, zz, dtmp, dlamda, wkeep,
                                  indx, indxc, indxp, coltyp, rotc, rots, rotp, rotn,
                                  ctl, off, n, n1);
      k_mrot<<<(n+255)/256,256,0,stream>>>(Zmat, rotc, rots, rotp, rotn, ctl, off, n);
      k_mcopyA<<<n,256,0,stream>>>(dd, Zmat, Q2, dgrp, indx, ctl, off, n, n1);
      k_mcopyB<<<n,256,0,stream>>>(dd, Zmat, Q2, dgrp, ctl, off, n, n1);
      k_msec<<<(n+63)/64,64,0,stream>>>(dd, Zmat, dlamda, wkeep, ctl, off);
      k_mzhat<<<(n+63)/64,64,0,stream>>>(dlamda, wkeep, what, Zmat, ctl, off);
      k_mvec<<<n,256,0,stream>>>(Zmat, what, indxc, ctl, off);
      int gcs = ((n*n)+255)/256; if (gcs > 16384) gcs = 16384;
      k_mcopyS<<<gcs,256,0,stream>>>(Smat, Zmat, ctl, off, 1);
      dim3 gg((n+31)/32,(n+31)/32);
      k_sgemm_dc<<<gg,256,0,stream>>>(Zmat, Q2, Smat, ctl, off, n, n1, 1);
      k_mcopyS<<<gcs,256,0,stream>>>(Smat, Zmat, ctl, off, 2);
      k_sgemm_dc<<<gg,256,0,stream>>>(Zmat, Q2, Smat, ctl, off, n, n1, 2);
      k_mmerge<<<1,1,0,stream>>>(dd, indxq, ctl, off, n);
    }
  }
  k_fpermA<<<DN,256,0,stream>>>(dd, Zmat, Q2, dtmp, indxq);
  k_fpermB<<<DN,256,0,stream>>>(evals, Zmat, Q2, dtmp, ctl);

  /* evo output now: Smat region is dead, evals lives in d_ws */
  k_outEvo<<<((Ttot*DN)+255)/256,256,0,stream>>>(evals, dt, out + 2*N2, Ttot);

  /* 4. cunmqr on split planes: Cre = Zmat (in place), Cim = 0 */
  k_zeroZ<<<(DN*DN+255)/256,256,0,stream>>>(Cim);
  int Krefl = DN-1;
  for (int i0 = ((Krefl-1)/NB)*NB; i0 >= 0; i0 -= NB){
    int ib = Krefl - i0; if (ib > NB) ib = NB;
    int m = DN-1-i0;
    int row0 = i0+1;
    k_packV<<<((m*ib)+255)/256,256,0,stream>>>(AH, Vp, i0, ib, m);
    k_vhv<<<ib,256,0,stream>>>(Vp, vhv, m, ib);
    k_bldT<<<1,64,0,stream>>>(vhv, tauA+i0, Tm, ib);
    dim3 gct((ib+31)/32,(DN+31)/32);
    k_cgemm_ct_p<<<gct,256,0,stream>>>(Vp, Cre, Cim, G1, row0, m, ib);
    k_cgemm_nn<<<gct,256,0,stream>>>(Tm, NB, G1, NB, G2, NB, ib, DN, ib);
    dim3 gup((m+31)/32,(DN+31)/32);
    k_cupdate_p<<<gup,256,0,stream>>>(Vp, G2, Cre, Cim, row0, m, ib);
  }

  /* 5. V outputs (AH now dead) */
  k_outVre<<<(DN*DN+255)/256,256,0,stream>>>(Cre, out);
  k_outVinv<<<(DN*DN+255)/256,256,0,stream>>>(Cre, out + N2);
}

// Round 5
// 159425.903 us; speedup vs baseline: 4.6529x; 4.6529x over previous
//
#include <hip/hip_runtime.h>
#include <math.h>

#define DN 2048
#define LEAF 16
#define NLEAVES 128
#define NB 64
#define SPLITK 32
#define EPSF 5.9604645e-08f      /* slamch('E') = 2^-24 */
#define SAFMINF 1.17549435e-38f

typedef float2 cplx;

struct Ctl {
  float orgnrm;
  int K;
  int ctot[4];
  float rho;
  int nrot;
  int n12, n23;
};

__device__ __forceinline__ cplx mkc(float x, float y){ cplx c; c.x=x; c.y=y; return c; }
__device__ __forceinline__ cplx cmul(cplx a, cplx b){ return mkc(a.x*b.x - a.y*b.y, a.x*b.y + a.y*b.x); }
__device__ __forceinline__ cplx cconj(cplx a){ return mkc(a.x, -a.y); }
__device__ __forceinline__ cplx cadd(cplx a, cplx b){ return mkc(a.x+b.x, a.y+b.y); }
__device__ __forceinline__ cplx cinv(cplx b){
  if (fabsf(b.x) >= fabsf(b.y)) { float r = b.y/b.x; float den = b.x + b.y*r; return mkc(1.f/den, -r/den); }
  else { float r = b.x/b.y; float den = b.x*r + b.y; return mkc(r/den, -1.f/den); }
}

/* ---------------- build H = i*(triu(sk,1) - triu(sk,1)^T), column-major ---------------- */
__global__ void k_buildH(const float* sk, cplx* AH){
  int idx = blockIdx.x*256 + threadIdx.x;
  if (idx >= DN*DN) return;
  int c = idx / DN, r = idx % DN;
  float im;
  if (r > c) im = -sk[(size_t)c*DN + r];
  else if (r < c) im = sk[(size_t)r*DN + c];
  else im = 0.f;
  AH[(size_t)c*DN + r] = mkc(copysignf(0.f, im), im);
}

/* ---------------- chetd2 (lower) step kernels ---------------- */
__global__ void k_clarfg(cplx* AH, cplx* tau, float* e, int j){
  __shared__ float red[256];
  __shared__ cplx ssc; __shared__ int sdo;
  int t = threadIdx.x;
  cplx* col = AH + (size_t)j*DN;
  float ssq = 0.f;
  for (int r = j+2+t; r < DN; r += 256){ cplx v = col[r]; ssq += v.x*v.x + v.y*v.y; }
  red[t]=ssq; __syncthreads();
  for (int s=128;s>0;s>>=1){ if (t<s) red[t]+=red[t+s]; __syncthreads(); }
  if (t==0){
    float xnorm = sqrtf(red[0]);
    cplx alpha = col[j+1];
    if (xnorm == 0.f && alpha.y == 0.f){
      tau[j] = mkc(0.f,0.f); e[j] = alpha.x; sdo = 0;
    } else {
      float beta = -copysignf(sqrtf(alpha.x*alpha.x + alpha.y*alpha.y + xnorm*xnorm), alpha.x);
      tau[j] = mkc((beta - alpha.x)/beta, -alpha.y/beta);
      ssc = cinv(mkc(alpha.x - beta, alpha.y));
      e[j] = beta;
      col[j+1] = mkc(beta, 0.f);
      sdo = 1;
    }
  }
  __syncthreads();
  if (sdo){ cplx sc = ssc; for (int r=j+2+t; r<DN; r+=256) col[r] = cmul(col[r], sc); }
}

/* split-K hermitian matvec: wpart[s][i] = sum over k-chunk s of A(i,c)*v(c) */
__global__ void k_gemv_split(const cplx* AH, cplx* wpart, int j, int m, int chunk){
  int i = blockIdx.x*256 + threadIdx.x;
  int s = blockIdx.y;
  if (i >= m) return;
  int c0 = s*chunk;
  int c1 = c0 + chunk; if (c1 > m) c1 = m;
  const cplx* vcol = AH + (size_t)j*DN + (j+1);
  cplx acc = mkc(0.f,0.f);
  for (int c = c0; c < c1; ++c){
    cplx a = AH[(size_t)(j+1+c)*DN + (j+1+i)];
    cplx v = (c==0)? mkc(1.f,0.f) : vcol[c];
    acc.x += a.x*v.x - a.y*v.y;
    acc.y += a.x*v.y + a.y*v.x;
  }
  wpart[(size_t)s*DN + i] = acc;
}

/* reduce partials, scale by tau, compute alpha = -tau/2 * (w^H v), finalize w */
__global__ void k_axpy(const cplx* AH, const cplx* wpart, cplx* w, const cplx* tau, int j, int m){
  __shared__ float rx[256], ry[256];
  __shared__ cplx salpha;
  int t = threadIdx.x;
  cplx tj = tau[j];
  const cplx* vcol = AH + (size_t)j*DN + (j+1);
  float dx=0.f, dy=0.f;
  for (int i=t; i<m; i+=256){
    cplx acc = mkc(0.f,0.f);
    #pragma unroll
    for (int s=0;s<SPLITK;s++){ cplx p = wpart[(size_t)s*DN + i]; acc.x += p.x; acc.y += p.y; }
    cplx w1 = cmul(tj, acc);
    w[i] = w1;
    cplx v = (i==0)? mkc(1.f,0.f) : vcol[i];
    dx += w1.x*v.x + w1.y*v.y;      /* conj(w)*v */
    dy += w1.x*v.y - w1.y*v.x;
  }
  rx[t]=dx; ry[t]=dy; __syncthreads();
  for (int s=128;s>0;s>>=1){ if (t<s){ rx[t]+=rx[t+s]; ry[t]+=ry[t+s]; } __syncthreads(); }
  if (t==0){ cplx dot = mkc(rx[0], ry[0]); cplx a = cmul(tj, dot); salpha = mkc(-0.5f*a.x, -0.5f*a.y); }
  __syncthreads();
  cplx al = salpha;
  for (int i=t; i<m; i+=256){ cplx v = (i==0)? mkc(1.f,0.f) : vcol[i]; w[i] = cadd(w[i], cmul(al, v)); }
}

/* r on low lanes for coalesced writes */
__global__ void k_her2(cplx* AH, const cplx* w, int j, int m){
  int r = blockIdx.x*32 + (threadIdx.x & 31);
  int c = blockIdx.y*8 + (threadIdx.x >> 5);
  if (r >= m || c >= m) return;
  const cplx* vcol = AH + (size_t)j*DN + (j+1);
  cplx vr = (r==0)? mkc(1.f,0.f) : vcol[r];
  cplx vc = (c==0)? mkc(1.f,0.f) : vcol[c];
  cplx wr = w[r], wc = w[c];
  cplx u = cadd(cmul(vr, cconj(wc)), cmul(wr, cconj(vc)));
  size_t idx = (size_t)(j+1+c)*DN + (j+1+r);
  AH[idx].x -= u.x; AH[idx].y -= u.y;
}

__global__ void k_collectD(const cplx* AH, float* d){
  int i = blockIdx.x*256 + threadIdx.x;
  if (i < DN) d[i] = AH[(size_t)i*DN + i].x;
}

__global__ void k_zeroZ(float* Z){
  int idx = blockIdx.x*256 + threadIdx.x;
  if (idx < DN*DN) Z[idx] = 0.f;
}

/* ---------------- sstedc prep: norm, scale, tear, indxq ---------------- */
__global__ void k_predc(float* d, float* e, int* indxq, Ctl* ctl){
  __shared__ float red[256];
  int t = threadIdx.x;
  float mx = 0.f;
  for (int i=t;i<DN;i+=256) mx = fmaxf(mx, fabsf(d[i]));
  for (int i=t;i<DN-1;i+=256) mx = fmaxf(mx, fabsf(e[i]));
  red[t]=mx; __syncthreads();
  for (int s=128;s>0;s>>=1){ if (t<s) red[t]=fmaxf(red[t],red[t+s]); __syncthreads(); }
  float orgnrm = red[0];
  if (t==0) ctl->orgnrm = orgnrm;
  float mul = 1.f/orgnrm;
  __syncthreads();
  for (int i=t;i<DN;i+=256) d[i]*=mul;
  for (int i=t;i<DN-1;i+=256) e[i]*=mul;
  __syncthreads();
  if (t==0){
    for (int b=1;b<NLEAVES;b++){ int s0=b*LEAF; float ae=fabsf(e[s0-1]); d[s0-1]-=ae; d[s0]-=ae; }
  }
  for (int i=t;i<DN;i+=256) indxq[i] = (i & (LEAF-1)) + 1;
}

/* ---------------- ssteqr (small, serial) ---------------- */
__device__ void slaev2_d(float a, float b, float c, float* rt1, float* rt2, float* cs1, float* sn1){
  float sm = a + c, df = a - c, adf = fabsf(df), tb = b + b, ab = fabsf(tb);
  float acmx, acmn;
  if (fabsf(a) > fabsf(c)) { acmx = a; acmn = c; } else { acmx = c; acmn = a; }
  float rt;
  if (adf > ab) rt = adf*sqrtf(1.f + (ab/adf)*(ab/adf));
  else if (adf < ab) rt = ab*sqrtf(1.f + (adf/ab)*(adf/ab));
  else rt = ab*sqrtf(2.f);
  int sgn1;
  if (sm < 0.f){ *rt1 = 0.5f*(sm - rt); sgn1 = -1; *rt2 = (acmx/(*rt1))*acmn - (b/(*rt1))*b; }
  else if (sm > 0.f){ *rt1 = 0.5f*(sm + rt); sgn1 = 1; *rt2 = (acmx/(*rt1))*acmn - (b/(*rt1))*b; }
  else { *rt1 = 0.5f*rt; *rt2 = -0.5f*rt; sgn1 = 1; }
  float cs; int sgn2;
  if (df >= 0.f){ cs = df + rt; sgn2 = 1; } else { cs = df - rt; sgn2 = -1; }
  float acs = fabsf(cs);
  if (acs > ab){ float ct = -tb/cs; *sn1 = 1.f/sqrtf(1.f + ct*ct); *cs1 = ct*(*sn1); }
  else {
    if (ab == 0.f){ *cs1 = 1.f; *sn1 = 0.f; }
    else { float tn = -cs/tb; *cs1 = 1.f/sqrtf(1.f + tn*tn); *sn1 = tn*(*cs1); }
  }
  if (sgn1 == sgn2){ float tn = *cs1; *cs1 = -(*sn1); *sn1 = tn; }
}

/* LAPACK >=3.10 convention: c >= 0 always */
__device__ void slartg_d(float f, float g, float* cs, float* sn, float* r){
  if (g == 0.f){ *cs = 1.f; *sn = 0.f; *r = f; }
  else if (f == 0.f){ *cs = 0.f; *sn = copysignf(1.f, g); *r = fabsf(g); }
  else {
    float d = sqrtf(f*f + g*g);
    *cs = fabsf(f)/d;
    *r = copysignf(d, f);
    *sn = g/(*r);
  }
}

__device__ void rot1_d(float* z, int ldz, int nr, int col, float cc, float ss){
  for (int r=0;r<nr;++r){
    float tmp = z[(col+1)*ldz + r];
    z[(col+1)*ldz + r] = cc*tmp - ss*z[col*ldz + r];
    z[col*ldz + r] = ss*tmp + cc*z[col*ldz + r];
  }
}

__device__ void ssteqr_small(int n, float* d, float* e, float* z, int ldz){
  for (int c=0;c<n;c++) for (int r=0;r<n;r++) z[c*ldz+r] = (r==c)?1.f:0.f;
  const float eps=EPSF, eps2=eps*eps, safmin=SAFMINF;
  int nmaxit = n*30, jtot=0;
  int l1=0;
  float wc[LEAF], ws_[LEAF];
  while (1){
    if (l1 > n-1) break;
    if (l1 > 0) e[l1-1] = 0.f;
    int m;
    for (m = l1; m <= n-2; ++m){
      float tst = fabsf(e[m]);
      if (tst == 0.f) break;
      if (tst <= (sqrtf(fabsf(d[m]))*sqrtf(fabsf(d[m+1])))*eps){ e[m]=0.f; break; }
    }
    int l = l1, lend = m;
    l1 = m+1;
    if (lend == l) continue;
    if (fabsf(d[lend]) < fabsf(d[l])){ int tmp=l; l=lend; lend=tmp; }
    if (lend > l){
      /* QL */
      while (1){
        int mm;
        if (l != lend){
          for (mm = l; mm <= lend-1; ++mm){
            float tst = e[mm]*e[mm];
            if (tst <= (eps2*fabsf(d[mm]))*fabsf(d[mm+1]) + safmin) break;
          }
        } else mm = lend;
        if (mm < lend) e[mm] = 0.f;
        float p = d[l];
        if (mm == l){ d[l]=p; l++; if (l<=lend) continue; else break; }
        if (mm == l+1){
          float rt1, rt2, c_, s_;
          slaev2_d(d[l], e[l], d[l+1], &rt1, &rt2, &c_, &s_);
          rot1_d(z, ldz, n, l, c_, s_);
          d[l]=rt1; d[l+1]=rt2; e[l]=0.f;
          l += 2; if (l<=lend) continue; else break;
        }
        if (jtot == nmaxit) break;
        jtot++;
        float g = (d[l+1]-p)/(2.f*e[l]);
        float rr = sqrtf(g*g+1.f);
        g = d[mm] - p + e[l]/(g + copysignf(rr, g));
        float s_ = 1.f, c_ = 1.f; p = 0.f;
        for (int i = mm-1; i >= l; --i){
          float f = s_*e[i], b = c_*e[i];
          slartg_d(g, f, &c_, &s_, &rr);
          if (i != mm-1) e[i+1] = rr;
          g = d[i+1] - p;
          rr = (d[i]-g)*s_ + 2.f*c_*b;
          p = s_*rr;
          d[i+1] = g+p;
          g = c_*rr - b;
          wc[i] = c_; ws_[i] = -s_;
        }
        for (int q = mm-1; q >= l; --q) rot1_d(z, ldz, n, q, wc[q], ws_[q]);   /* 'B' */
        d[l] = d[l] - p; e[l] = g;
      }
    } else {
      /* QR */
      while (1){
        int mm;
        if (l != lend){
          for (mm = l; mm >= lend+1; --mm){
            float tst = e[mm-1]*e[mm-1];
            if (tst <= (eps2*fabsf(d[mm]))*fabsf(d[mm-1]) + safmin) break;
          }
        } else mm = lend;
        if (mm > lend) e[mm-1] = 0.f;
        float p = d[l];
        if (mm == l){ d[l]=p; l--; if (l>=lend) continue; else break; }
        if (mm == l-1){
          float rt1, rt2, c_, s_;
          slaev2_d(d[l-1], e[l-1], d[l], &rt1, &rt2, &c_, &s_);
          rot1_d(z, ldz, n, l-1, c_, s_);
          d[l-1]=rt1; d[l]=rt2; e[l-1]=0.f;
          l -= 2; if (l>=lend) continue; else break;
        }
        if (jtot == nmaxit) break;
        jtot++;
        float g = (d[l-1]-p)/(2.f*e[l-1]);
        float rr = sqrtf(g*g+1.f);
        g = d[mm] - p + e[l-1]/(g + copysignf(rr, g));
        float s_=1.f, c_=1.f; p=0.f;
        for (int i = mm; i <= l-1; ++i){
          float f = s_*e[i], b = c_*e[i];
          slartg_d(g, f, &c_, &s_, &rr);
          if (i != mm) e[i-1] = rr;
          g = d[i] - p;
          rr = (d[i+1]-g)*s_ + 2.f*c_*b;
          p = s_*rr;
          d[i] = g+p;
          g = c_*rr - b;
          wc[i] = c_; ws_[i] = s_;
        }
        for (int q = mm; q <= l-1; ++q) rot1_d(z, ldz, n, q, wc[q], ws_[q]);  /* 'F' */
        d[l] = d[l]-p; e[l-1] = g;
      }
    }
  }
  /* selection sort ascending + column swap */
  for (int ii=1; ii<n; ++ii){
    int i = ii-1, k = i; float pp = d[i];
    for (int jj=ii; jj<n; ++jj) if (d[jj] < pp){ k=jj; pp=d[jj]; }
    if (k != i){
      d[k]=d[i]; d[i]=pp;
      for (int r=0;r<n;r++){ float tv=z[i*ldz+r]; z[i*ldz+r]=z[k*ldz+r]; z[k*ldz+r]=tv; }
    }
  }
}

__global__ void k_leaves(float* d, float* e, float* Zmat){
  __shared__ float sd[LEAF], se[LEAF], sz[LEAF*LEAF];
  int off = blockIdx.x*LEAF;
  int t = threadIdx.x;
  if (t < LEAF){ sd[t] = d[off+t]; se[t] = (t<LEAF-1)? e[off+t] : 0.f; }
  __syncthreads();
  if (t==0) ssteqr_small(LEAF, sd, se, sz, LEAF);
  __syncthreads();
  if (t < LEAF){ d[off+t]=sd[t]; if (t<LEAF-1) e[off+t]=se[t]; }
  for (int i=t; i<LEAF*LEAF; i+=64){
    int c = i/LEAF, r = i%LEAF;
    Zmat[(size_t)(off+c)*DN + (off+r)] = sz[c*LEAF+r];
  }
}

/* ---------------- merge: slaed1/slaed2 prep (serial core on thread 0) ---------------- */
__global__ void k_mprep(float* d, const float* e, const float* Zmat, int* indxq,
                        float* z, float* dtmp, float* dlamda, float* wkeep,
                        int* indx, int* indxc, int* indxp, int* coltyp,
                        float* rotc, float* rots, int* rotp, int* rotn,
                        Ctl* ctl, int off, int n, int n1)
{
  __shared__ float red[256];
  int t = threadIdx.x; int n2 = n - n1;
  float rho0 = e[off + n1 - 1];
  for (int c = t; c < n; c += 256){
    float val = (c < n1) ? Zmat[(size_t)(off+c)*DN + (off+n1-1)]
                         : Zmat[(size_t)(off+c)*DN + (off+n1)];
    if (c >= n1){ if (rho0 < 0.f) val = -val; indxq[off+c] += n1; }
    z[c] = val * 0.70710678118654752440f;
  }
  __syncthreads();
  for (int i = t; i < n; i += 256) dtmp[i] = d[off + indxq[off+i] - 1];
  __syncthreads();
  if (t == 0){
    int i1=0, i2=n1, ns1=n1, ns2=n2, k=0;
    while (ns1>0 && ns2>0){
      if (dtmp[i1] <= dtmp[i2]){ indxc[k++]=i1+1; i1++; ns1--; }
      else { indxc[k++]=i2+1; i2++; ns2--; }
    }
    while (ns1>0){ indxc[k++]=i1+1; i1++; ns1--; }
    while (ns2>0){ indxc[k++]=i2+1; i2++; ns2--; }
  }
  __syncthreads();
  /* NOTE: indx is stored 0-BASED (indxq values are 1-based) */
  for (int i = t; i < n; i += 256) indx[i] = indxq[off + indxc[i] - 1] - 1;
  __syncthreads();
  float mz=0.f, md=0.f;
  for (int i=t;i<n;i+=256){ mz = fmaxf(mz, fabsf(z[i])); md = fmaxf(md, fabsf(d[off+i])); }
  red[t]=mz; __syncthreads();
  for (int s=128;s>0;s>>=1){ if (t<s) red[t]=fmaxf(red[t],red[t+s]); __syncthreads(); }
  mz = red[0]; __syncthreads();
  red[t]=md; __syncthreads();
  for (int s=128;s>0;s>>=1){ if (t<s) red[t]=fmaxf(red[t],red[t+s]); __syncthreads(); }
  md = red[0];
  if (t == 0){
    float rho = fabsf(2.f*rho0);
    float tol = 8.f*EPSF*fmaxf(md, mz);
    ctl->rho = rho;
    if (rho*mz <= tol){
      /* all deflated: indx (sorted order) drives the copy kernels */
      ctl->K = 0; ctl->nrot = 0;
      ctl->ctot[0]=0; ctl->ctot[1]=0; ctl->ctot[2]=0; ctl->ctot[3]=n;
      ctl->n12 = 0; ctl->n23 = 0;
    } else {
      for (int i=0;i<n1;i++) coltyp[i]=0;
      for (int i=n1;i<n;i++) coltyp[i]=2;
      int K=0, k2=n, nrot=0, pj=0;
      int jj=0;
      for (; jj<n; ++jj){
        int nj = indx[jj];
        if (rho*fabsf(z[nj]) <= tol){ k2--; coltyp[nj]=3; indxp[k2]=nj; }
        else { pj = nj; break; }
      }
      for (;;){
        jj++;
        if (jj >= n) break;
        int nj = indx[jj];
        if (rho*fabsf(z[nj]) <= tol){ k2--; coltyp[nj]=3; indxp[k2]=nj; }
        else {
          float s_ = z[pj], c_ = z[nj];
          float tau_ = sqrtf(c_*c_ + s_*s_);
          float tt = d[off+nj] - d[off+pj];
          c_ = c_/tau_; s_ = -s_/tau_;
          if (fabsf(tt*c_*s_) <= tol){
            z[nj] = tau_; z[pj] = 0.f;
            if (coltyp[nj] != coltyp[pj]) coltyp[nj] = 1;
            coltyp[pj] = 3;
            rotp[nrot]=pj; rotn[nrot]=nj; rotc[nrot]=c_; rots[nrot]=s_; nrot++;
            float t2 = d[off+pj]*c_*c_ + d[off+nj]*s_*s_;
            d[off+nj] = d[off+pj]*s_*s_ + d[off+nj]*c_*c_;
            d[off+pj] = t2;
            k2--;
            int ii = 1;
            for (;;){
              if (k2+ii <= n-1){
                if (d[off+pj] < d[off+indxp[k2+ii]]){ indxp[k2+ii-1]=indxp[k2+ii]; indxp[k2+ii]=pj; ii++; }
                else { indxp[k2+ii-1]=pj; break; }
              } else { indxp[k2+ii-1]=pj; break; }
            }
            pj = nj;
          } else {
            dlamda[K]=d[off+pj]; wkeep[K]=z[pj]; indxp[K]=pj; K++;
            pj = nj;
          }
        }
      }
      dlamda[K]=d[off+pj]; wkeep[K]=z[pj]; indxp[K]=pj; K++;
      int ct[4]={0,0,0,0};
      for (int q=0;q<n;q++) ct[coltyp[q]]++;
      int psm[4]; psm[0]=0; psm[1]=ct[0]; psm[2]=ct[0]+ct[1]; psm[3]=ct[0]+ct[1]+ct[2];
      for (int q=0;q<n;q++){
        int js = indxp[q]; int cc = coltyp[js];
        indx[psm[cc]] = js; indxc[psm[cc]] = q; psm[cc]++;
      }
      ctl->K = K; ctl->nrot = nrot;
      ctl->ctot[0]=ct[0]; ctl->ctot[1]=ct[1]; ctl->ctot[2]=ct[2]; ctl->ctot[3]=ct[3];
      ctl->n12 = ct[0]+ct[1]; ctl->n23 = ct[1]+ct[2];
    }
  }
}

__global__ void k_mrot(float* Zmat, const float* rotc, const float* rots,
                       const int* rotp, const int* rotn, const Ctl* ctl, int off, int n){
  int r = blockIdx.x*256 + threadIdx.x;
  if (r >= n) return;
  int nrot = ctl->nrot;
  for (int q=0;q<nrot;++q){
    size_t ip = (size_t)(off+rotp[q])*DN + off + r;
    size_t in_ = (size_t)(off+rotn[q])*DN + off + r;
    float x = Zmat[ip], y = Zmat[in_];
    float cc = rotc[q], ss = rots[q];
    Zmat[ip]  = cc*x + ss*y;
    Zmat[in_] = cc*y - ss*x;
  }
}

__global__ void k_mcopyA(const float* d, const float* Zmat, float* Q2, float* dgrp,
                         const int* indx, const Ctl* ctl, int off, int n, int n1){
  int p = blockIdx.x; if (p >= n) return;
  int t = threadIdx.x; int n2 = n - n1;
  int c0 = ctl->ctot[0], c1 = ctl->ctot[1], c2 = ctl->ctot[2];
  int K = c0+c1+c2;
  int src = indx[p];
  const float* qcol = Zmat + (size_t)(off+src)*DN + off;
  if (t == 0) dgrp[p] = d[off+src];
  size_t base2 = (size_t)n1*(c0+c1);
  size_t base3 = base2 + (size_t)n2*(c1+c2);
  if (p < c0){
    float* dst = Q2 + (size_t)p*n1;
    for (int r=t;r<n1;r+=256) dst[r] = qcol[r];
  } else if (p < c0+c1){
    float* d1 = Q2 + (size_t)p*n1;
    float* d2 = Q2 + base2 + (size_t)(p-c0)*n2;
    for (int r=t;r<n1;r+=256) d1[r] = qcol[r];
    for (int r=t;r<n2;r+=256) d2[r] = qcol[n1+r];
  } else if (p < K){
    float* d2 = Q2 + base2 + (size_t)(p-c0)*n2;
    for (int r=t;r<n2;r+=256) d2[r] = qcol[n1+r];
  } else {
    float* dst = Q2 + base3 + (size_t)(p-K)*n;
    for (int r=t;r<n;r+=256) dst[r] = qcol[r];
  }
}

__global__ void k_mcopyB(float* d, float* Zmat, const float* Q2, const float* dgrp,
                         const Ctl* ctl, int off, int n, int n1){
  int p = blockIdx.x; if (p >= n) return;
  int t = threadIdx.x; int n2 = n - n1;
  int c0 = ctl->ctot[0], c1 = ctl->ctot[1], c2 = ctl->ctot[2];
  int K = c0+c1+c2;
  if (p < K) return;
  size_t base3 = (size_t)n1*(c0+c1) + (size_t)n2*(c1+c2);
  const float* src = Q2 + base3 + (size_t)(p-K)*n;
  float* dst = Zmat + (size_t)(off+p)*DN + off;
  for (int r=t;r<n;r+=256) dst[r] = src[r];
  if (t==0) d[off+p] = dgrp[p];
}

/* ---------------- secular equation solver (slaed4-style, shifted coordinates) ---------------- */
__global__ void k_msec(float* d, float* Zmat, const float* dl, const float* w,
                       const Ctl* ctl, int off){
  int j = blockIdx.x*64 + threadIdx.x;
  int K = ctl->K;
  if (j >= K) return;
  float rho = ctl->rho;
  float* delta = Zmat + (size_t)(off+j)*DN + off;
  if (K == 1){
    d[off] = dl[0] + rho*w[0]*w[0];
    delta[0] = 1.f;
    return;
  }
  int orig; float lo, hi;
  if (j < K-1){
    float gap = dl[j+1] - dl[j];
    float half = 0.5f*gap;
    float fmid = 1.f;
    for (int l=0;l<K;l++){
      float D = (dl[l]-dl[j]) - half;
      fmid += rho*w[l]*w[l]/D;
    }
    if (fmid >= 0.f){ orig = j;   lo = 0.f;   hi = half; }
    else            { orig = j+1; lo = -half; hi = 0.f;  }
  } else {
    float s2 = 0.f;
    for (int l=0;l<K;l++) s2 += w[l]*w[l];
    orig = K-1; lo = 0.f; hi = rho*s2*1.000002f + 1e-30f;
  }
  float dorig = dl[orig];
  float eta = 0.5f*(lo+hi);
  for (int it=0; it<50; ++it){
    float g = 1.f, gp = 0.f;
    for (int l=0;l<K;l++){
      float del = (dl[l]-dorig) - eta;
      float r = w[l]/del;
      g  += rho*w[l]*r;
      gp += rho*r*r;
    }
    if (g > 0.f) hi = eta; else lo = eta;
    float etan = eta - g/gp;
    if (!(etan > lo && etan < hi)) etan = 0.5f*(lo+hi);
    if (etan == eta) break;
    eta = etan;
  }
  d[off+j] = dorig + eta;
  for (int l=0;l<K;l++) delta[l] = (dl[l]-dorig) - eta;
}

__global__ void k_mzhat(const float* dlamda, const float* wkeep, float* what,
                        const float* Zmat, const Ctl* ctl, int off){
  int K = ctl->K;
  int i = blockIdx.x*64 + threadIdx.x;
  if (i >= K) return;
  float acc = Zmat[(size_t)(off+i)*DN + off+i];
  float di = dlamda[i];
  for (int jj=0;jj<K;jj++){
    if (jj==i) continue;
    acc *= Zmat[(size_t)(off+jj)*DN + off+i] / (di - dlamda[jj]);
  }
  what[i] = copysignf(sqrtf(fabsf(acc)), wkeep[i]);
}

__global__ void k_mvec(float* Zmat, const float* what, const int* indxc,
                       const Ctl* ctl, int off){
  __shared__ float sv[2048];
  __shared__ float red[256];
  int K = ctl->K; int j = blockIdx.x;
  if (j >= K) return;
  int t = threadIdx.x;
  float* col = Zmat + (size_t)(off+j)*DN + off;
  float ssq = 0.f;
  for (int i=t;i<K;i+=256){
    float den = col[i];
    if (den == 0.f) den = 1e-30f;
    float v = what[i]/den; sv[i]=v; ssq += v*v;
  }
  red[t]=ssq; __syncthreads();
  for (int s=128;s>0;s>>=1){ if (t<s) red[t]+=red[t+s]; __syncthreads(); }
  float temp = sqrtf(red[0]);
  for (int i=t;i<K;i+=256) col[i] = sv[indxc[i]]/temp;
}

__global__ void k_mcopyS(float* Smat, const float* Zmat, const Ctl* ctl, int off, int mode){
  int K = ctl->K; if (K==0) return;
  int rows = (mode==1)? ctl->n23 : ctl->n12;
  int rowoff = (mode==1)? ctl->ctot[0] : 0;
  if (rows==0) return;
  size_t tot = (size_t)rows*K;
  for (size_t idx = (size_t)blockIdx.x*256+threadIdx.x; idx < tot; idx += (size_t)gridDim.x*256){
    int r = (int)(idx % rows); int c = (int)(idx / rows);
    Smat[idx] = Zmat[(size_t)(off+c)*DN + off + rowoff + r];
  }
}

__global__ void k_sgemm_dc(float* Zmat, const float* Q2, const float* Smat,
                           const Ctl* ctl, int off, int n, int n1, int mode){
  int K = ctl->K; if (K==0) return;
  int n2 = n-n1;
  int m, kk; const float* A; int lda; float* C;
  if (mode==1){ m=n2; kk=ctl->n23; A = Q2 + (size_t)n1*ctl->n12; lda=n2; C = Zmat + (size_t)off*DN + off+n1; }
  else { m=n1; kk=ctl->n12; A = Q2; lda=n1; C = Zmat + (size_t)off*DN + off; }
  const float* B = Smat; int ldb = kk;
  int tr = blockIdx.x*32, tc = blockIdx.y*32;
  if (tr >= m || tc >= K) return;
  __shared__ float As[32][33], Bs[32][33];
  int tx = threadIdx.x & 31, ty = threadIdx.x >> 5;
  float acc[4] = {0.f,0.f,0.f,0.f};
  for (int k0=0;k0<kk;k0+=32){
    for (int q=0;q<4;q++){ int kc=k0+ty+q*8; int r=tr+tx;
      As[tx][ty+q*8] = (r<m && kc<kk)? A[(size_t)kc*lda + r] : 0.f; }
    for (int q=0;q<4;q++){ int cc=tc+ty+q*8; int kr=k0+tx;
      Bs[tx][ty+q*8] = (kr<kk && cc<K)? B[(size_t)cc*ldb + kr] : 0.f; }
    __syncthreads();
    for (int kq=0;kq<32;kq++){
      float a = As[tx][kq];
      #pragma unroll
      for (int q=0;q<4;q++) acc[q] += a*Bs[kq][ty+q*8];
    }
    __syncthreads();
  }
  int r = tr+tx;
  if (r < m){
    for (int q=0;q<4;q++){ int c = tc+ty+q*8; if (c < K) C[(size_t)c*DN + r] = acc[q]; }
  }
}

__global__ void k_mmerge(float* d, int* indxq, const Ctl* ctl, int off, int n){
  int K = ctl->K;
  if (K == 0){ for (int i=0;i<n;i++) indxq[off+i]=i+1; return; }
  int i1=0, i2=n-1, ns1=K, ns2=n-K, k=0;
  while (ns1>0 && ns2>0){
    if (d[off+i1] <= d[off+i2]){ indxq[off+k++]=i1+1; i1++; ns1--; }
    else { indxq[off+k++]=i2+1; i2--; ns2--; }
  }
  while (ns1>0){ indxq[off+k++]=i1+1; i1++; ns1--; }
  while (ns2>0){ indxq[off+k++]=i2+1; i2--; ns2--; }
}

/* ---------------- final permutation + scale back ---------------- */
__global__ void k_fpermA(const float* d, const float* Zmat, float* Q2, float* dtmp, const int* indxq){
  int i = blockIdx.x; int t = threadIdx.x;
  int src = indxq[i]-1;
  if (t==0) dtmp[i] = d[src];
  const float* sc = Zmat + (size_t)src*DN;
  float* dc = Q2 + (size_t)i*DN;
  for (int r=t;r<DN;r+=256) dc[r]=sc[r];
}
__global__ void k_fpermB(float* evals, float* Zmat, const float* Q2, const float* dtmp, const Ctl* ctl){
  int i = blockIdx.x; int t = threadIdx.x;
  if (t==0) evals[i] = dtmp[i]*ctl->orgnrm;
  const float* sc = Q2 + (size_t)i*DN;
  float* dc = Zmat + (size_t)i*DN;
  for (int r=t;r<DN;r+=256) dc[r]=sc[r];
}

/* ---------------- cunmqr (blocked, left, no-transpose) on split re/im planes ---------------- */
__global__ void k_packV(const cplx* AH, cplx* Vp, int i0, int ib, int m){
  int idx = blockIdx.x*256 + threadIdx.x;
  if (idx >= m*ib) return;
  int r = idx % m, c = idx / m;
  int grow = i0+1+r, pc = i0+c+1;
  cplx v;
  if (grow < pc) v = mkc(0.f,0.f);
  else if (grow == pc) v = mkc(1.f,0.f);
  else v = AH[(size_t)(i0+c)*DN + grow];
  Vp[(size_t)c*m + r] = v;
}

__global__ void k_vhv(const cplx* Vp, cplx* vhv, int m, int ib){
  __shared__ float rx[256], ry[256];
  int c = blockIdx.x; if (c >= ib) return;
  int t = threadIdx.x;
  for (int r=0; r<c; ++r){
    float dx=0.f, dy=0.f;
    for (int rl=c+t; rl<m; rl+=256){
      cplx a = Vp[(size_t)r*m + rl];
      cplx b = Vp[(size_t)c*m + rl];
      dx += a.x*b.x + a.y*b.y;     /* conj(a)*b */
      dy += a.x*b.y - a.y*b.x;
    }
    rx[t]=dx; ry[t]=dy; __syncthreads();
    for (int s=128;s>0;s>>=1){ if (t<s){ rx[t]+=rx[t+s]; ry[t]+=ry[t+s]; } __syncthreads(); }
    if (t==0) vhv[r + c*NB] = mkc(rx[0], ry[0]);
    __syncthreads();
  }
}

__global__ void k_bldT(const cplx* vhv, const cplx* tau, cplx* T, int ib){
  int t = threadIdx.x;
  for (int idx=t; idx<NB*NB; idx+=64) T[idx] = mkc(0.f,0.f);
  __syncthreads();
  for (int c=0; c<ib; ++c){
    if (t < c){
      cplx acc = mkc(0.f,0.f);
      for (int q=t; q<c; ++q) acc = cadd(acc, cmul(T[t + q*NB], vhv[q + c*NB]));
      cplx nt = mkc(-tau[c].x, -tau[c].y);
      T[t + c*NB] = cmul(nt, acc);
    }
    if (t == c) T[c + c*NB] = tau[c];
    __syncthreads();
  }
}

/* G1(ib x DN) = Vp^H (m x ib) * C(planes, rows row0..row0+m) */
__global__ void k_cgemm_ct_p(const cplx* A, const float* Cre, const float* Cim,
                             cplx* G1, int row0, int m, int ib){
  __shared__ cplx As[32][33], Bs[32][33];
  int tr = blockIdx.x*32, tc = blockIdx.y*32;
  if (tr >= ib) return;
  int tx = threadIdx.x & 31, ty = threadIdx.x >> 5;
  cplx acc[4]; for (int q=0;q<4;q++) acc[q]=mkc(0.f,0.f);
  for (int k0=0;k0<m;k0+=32){
    for (int q=0;q<4;q++){ int rr=tr+ty+q*8; int kr=k0+tx;
      As[tx][ty+q*8] = (kr<m && rr<ib)? cconj(A[(size_t)rr*m + kr]) : mkc(0.f,0.f); }
    for (int q=0;q<4;q++){ int cc=tc+ty+q*8; int kr=k0+tx;
      if (kr<m && cc<DN){ size_t bi = (size_t)cc*DN + row0 + kr; Bs[tx][ty+q*8] = mkc(Cre[bi], Cim[bi]); }
      else Bs[tx][ty+q*8] = mkc(0.f,0.f); }
    __syncthreads();
    for (int kq=0;kq<32;kq++){
      cplx a = As[kq][tx];
      #pragma unroll
      for (int q=0;q<4;q++){
        cplx b = Bs[kq][ty+q*8];
        acc[q].x += a.x*b.x - a.y*b.y;
        acc[q].y += a.x*b.y + a.y*b.x;
      }
    }
    __syncthreads();
  }
  int r = tr+tx;
  if (r < ib){
    for (int q=0;q<4;q++){ int c=tc+ty+q*8; if (c<DN) G1[r + (size_t)c*NB] = acc[q]; }
  }
}

/* G2 = Tm * G1 (both small, interleaved) */
__global__ void k_cgemm_nn(const cplx* A, int lda, const cplx* B, int ldb,
                           cplx* C, int ldc, int m, int nn, int kk){
  __shared__ cplx As[32][33], Bs[32][33];
  int tr = blockIdx.x*32, tc = blockIdx.y*32;
  if (tr >= m || tc >= nn) return;
  int tx = threadIdx.x & 31, ty = threadIdx.x >> 5;
  cplx acc[4]; for (int q=0;q<4;q++) acc[q]=mkc(0.f,0.f);
  for (int k0=0;k0<kk;k0+=32){
    for (int q=0;q<4;q++){ int kc=k0+ty+q*8; int r=tr+tx;
      As[tx][ty+q*8] = (r<m && kc<kk)? A[(size_t)kc*lda + r] : mkc(0.f,0.f); }
    for (int q=0;q<4;q++){ int cc=tc+ty+q*8; int kr=k0+tx;
      Bs[tx][ty+q*8] = (kr<kk && cc<nn)? B[(size_t)cc*ldb + kr] : mkc(0.f,0.f); }
    __syncthreads();
    for (int kq=0;kq<32;kq++){
      cplx a = As[tx][kq];
      #pragma unroll
      for (int q=0;q<4;q++){
        cplx b = Bs[kq][ty+q*8];
        acc[q].x += a.x*b.x - a.y*b.y;
        acc[q].y += a.x*b.y + a.y*b.x;
      }
    }
    __syncthreads();
  }
  int r = tr+tx;
  if (r < m){
    for (int q=0;q<4;q++){ int c = tc+ty+q*8; if (c < nn) C[r + (size_t)c*NB] = acc[q]; }
  }
}

/* C(planes, rows row0..) -= Vp(m x ib) * G2(ib x DN, ld NB) */
__global__ void k_cupdate_p(const cplx* A, const cplx* G2, float* Cre, float* Cim,
                            int row0, int m, int ib){
  __shared__ cplx As[32][33], Bs[32][33];
  int tr = blockIdx.x*32, tc = blockIdx.y*32;
  if (tr >= m) return;
  int tx = threadIdx.x & 31, ty = threadIdx.x >> 5;
  cplx acc[4]; for (int q=0;q<4;q++) acc[q]=mkc(0.f,0.f);
  for (int k0=0;k0<ib;k0+=32){
    for (int q=0;q<4;q++){ int kc=k0+ty+q*8; int r=tr+tx;
      As[tx][ty+q*8] = (r<m && kc<ib)? A[(size_t)kc*m + r] : mkc(0.f,0.f); }
    for (int q=0;q<4;q++){ int cc=tc+ty+q*8; int kr=k0+tx;
      Bs[tx][ty+q*8] = (kr<ib && cc<DN)? G2[kr + (size_t)cc*NB] : mkc(0.f,0.f); }
    __syncthreads();
    for (int kq=0;kq<32;kq++){
      cplx a = As[tx][kq];
      #pragma unroll
      for (int q=0;q<4;q++){
        cplx b = Bs[kq][ty+q*8];
        acc[q].x += a.x*b.x - a.y*b.y;
        acc[q].y += a.x*b.y + a.y*b.x;
      }
    }
    __syncthreads();
  }
  int r = tr+tx;
  if (r < m){
    for (int q=0;q<4;q++){
      int c = tc+ty+q*8;
      if (c < DN){
        size_t idx = (size_t)c*DN + row0 + r;
        Cre[idx] -= acc[q].x;
        Cim[idx] -= acc[q].y;
      }
    }
  }
}

/* ---------------- outputs (real parts only) ---------------- */
__global__ void k_outVre(const float* Cre, float* out0){
  int idx = blockIdx.x*256 + threadIdx.x;
  if (idx >= DN*DN) return;
  int r = idx >> 11, c = idx & (DN-1);
  out0[idx] = Cre[(size_t)c*DN + r];           /* Re V, row-major */
}
__global__ void k_outVinv(const float* Cre, float* out1){
  int idx = blockIdx.x*256 + threadIdx.x;
  if (idx >= DN*DN) return;
  out1[idx] = Cre[idx];                         /* Re V^H row-major == Cre col-major linear */
}
__global__ void k_outEvo(const float* evals, const float* dt, float* out2, int T){
  int idx = blockIdx.x*256 + threadIdx.x;
  if (idx >= T*DN) return;
  int k = idx & (DN-1), tt = idx >> 11;
  out2[idx] = cosf(evals[k]*dt[tt]);            /* Re exp(-i*lambda*dt) */
}

/* ---------------- host ---------------- */
extern "C" void kernel_launch(void* const* d_in, const int* in_sizes, int n_in,
                              void* d_out, int out_size, void* d_ws, size_t ws_size,
                              hipStream_t stream)
{
  const float* sk = (const float*)d_in[0];
  const float* dt = (const float*)d_in[1];
  int Ttot = in_sizes[1];
  float* out = (float*)d_out;
  (void)ws_size; (void)n_in; (void)out_size;

  /* d_out = 3*N^2 floats (real parts only):
     [0, 2N^2)    : AH (cplx) -> Re(V) [0,N^2) + Re(Vinv) [N^2,2N^2) at end
     [2N^2, 3N^2) : Smat during D&C -> Re(evo) output
     d_ws:
     [0, N^2)     : Zmat == Cre
     [N^2, 2N^2)  : Q2   == Cim
     [2N^2, ...)  : small vectors + {wpart | cunmqr block scratch} (aliased) */
  const size_t N2 = (size_t)DN*DN;
  cplx*  AH   = (cplx*)out;
  float* Smat = out + 2*N2;
  float* Zmat = (float*)d_ws;           /* = Cre */
  float* Q2   = (float*)d_ws + N2;      /* = Cim */
  float* Cre  = Zmat;
  float* Cim  = Q2;

  char* wp = (char*)d_ws + 2*N2*sizeof(float);
  auto carve = [&](size_t b)->void*{ void* p=(void*)wp; wp += (b+255)&~(size_t)255; return p; };
  float* dd     = (float*)carve(DN*sizeof(float));
  float* ee     = (float*)carve(DN*sizeof(float));
  float* zz     = (float*)carve(DN*sizeof(float));
  float* dtmp   = (float*)carve(DN*sizeof(float));
  float* dlamda = (float*)carve(DN*sizeof(float));
  float* wkeep  = (float*)carve(DN*sizeof(float));
  float* what   = (float*)carve(DN*sizeof(float));
  float* dgrp   = (float*)carve(DN*sizeof(float));
  float* rotc   = (float*)carve(DN*sizeof(float));
  float* rots   = (float*)carve(DN*sizeof(float));
  float* evals  = (float*)carve(DN*sizeof(float));
  cplx*  tauA   = (cplx*)carve(DN*sizeof(cplx));
  cplx*  wvec   = (cplx*)carve(DN*sizeof(cplx));
  int*   indxq  = (int*)carve(DN*sizeof(int));
  int*   indx   = (int*)carve(DN*sizeof(int));
  int*   indxc  = (int*)carve(DN*sizeof(int));
  int*   indxp  = (int*)carve(DN*sizeof(int));
  int*   coltyp = (int*)carve(DN*sizeof(int));
  int*   rotp   = (int*)carve(DN*sizeof(int));
  int*   rotn   = (int*)carve(DN*sizeof(int));
  Ctl*   ctl    = (Ctl*)carve(sizeof(Ctl));
  cplx*  Vp     = (cplx*)carve((size_t)DN*NB*sizeof(cplx));   /* 1 MB */
  cplx*  G1     = (cplx*)carve((size_t)NB*DN*sizeof(cplx));
  cplx*  G2     = (cplx*)carve((size_t)NB*DN*sizeof(cplx));
  cplx*  Tm     = (cplx*)carve((size_t)NB*NB*sizeof(cplx));
  cplx*  vhv    = (cplx*)carve((size_t)NB*NB*sizeof(cplx));
  /* wpart (phase 2 only) aliases Vp (phase 4 only): SPLITK*DN cplx = 512 KB <= 1 MB */
  cplx*  wpart  = Vp;

  /* 1. build H */
  k_buildH<<<(DN*DN+255)/256,256,0,stream>>>(sk, AH);

  /* 2. chetd2 lower (unblocked, split-K matvec) */
  for (int j=0; j<=DN-2; ++j){
    int m = DN-1-j;
    k_clarfg<<<1,256,0,stream>>>(AH, tauA, ee, j);
    int chunk = (m + SPLITK - 1)/SPLITK;
    dim3 gv((m+255)/256, SPLITK);
    k_gemv_split<<<gv,256,0,stream>>>(AH, wpart, j, m, chunk);
    k_axpy<<<1,256,0,stream>>>(AH, wpart, wvec, tauA, j, m);
    dim3 g2((m+31)/32,(m+7)/8);
    k_her2<<<g2,256,0,stream>>>(AH, wvec, j, m);
  }
  k_collectD<<<(DN+255)/256,256,0,stream>>>(AH, dd);

  /* 3. sstedc('I') equivalent (real D&C) */
  k_zeroZ<<<(DN*DN+255)/256,256,0,stream>>>(Zmat);
  k_predc<<<1,256,0,stream>>>(dd, ee, indxq, ctl);
  k_leaves<<<NLEAVES,64,0,stream>>>(dd, ee, Zmat);

  for (int sz = LEAF; sz < DN; sz *= 2){
    for (int off = 0; off < DN; off += 2*sz){
      int n = 2*sz, n1 = sz;
      k_mprep<<<1,256,0,stream>>>(dd, ee, Zmat, indxq, zz, dtmp, dlamda, wkeep,
                                  indx, indxc, indxp, coltyp, rotc, rots, rotp, rotn,
                                  ctl, off, n, n1);
      k_mrot<<<(n+255)/256,256,0,stream>>>(Zmat, rotc, rots, rotp, rotn, ctl, off, n);
      k_mcopyA<<<n,256,0,stream>>>(dd, Zmat, Q2, dgrp, indx, ctl, off, n, n1);
      k_mcopyB<<<n,256,0,stream>>>(dd, Zmat, Q2, dgrp, ctl, off, n, n1);
      k_msec<<<(n+63)/64,64,0,stream>>>(dd, Zmat, dlamda, wkeep, ctl, off);
      k_mzhat<<<(n+63)/64,64,0,stream>>>(dlamda, wkeep, what, Zmat, ctl, off);
      k_mvec<<<n,256,0,stream>>>(Zmat, what, indxc, ctl, off);
      int gcs = ((n*n)+255)/256; if (gcs > 16384) gcs = 16384;
      k_mcopyS<<<gcs,256,0,stream>>>(Smat, Zmat, ctl, off, 1);
      dim3 gg((n+31)/32,(n+31)/32);
      k_sgemm_dc<<<gg,256,0,stream>>>(Zmat, Q2, Smat, ctl, off, n, n1, 1);
      k_mcopyS<<<gcs,256,0,stream>>>(Smat, Zmat, ctl, off, 2);
      k_sgemm_dc<<<gg,256,0,stream>>>(Zmat, Q2, Smat, ctl, off, n, n1, 2);
      k_mmerge<<<1,1,0,stream>>>(dd, indxq, ctl, off, n);
    }
  }
  k_fpermA<<<DN,256,0,stream>>>(dd, Zmat, Q2, dtmp, indxq);
  k_fpermB<<<DN,256,0,stream>>>(evals, Zmat, Q2, dtmp, ctl);

  /* evo output now: Smat region is dead, evals lives in d_ws */
  k_outEvo<<<((Ttot*DN)+255)/256,256,0,stream>>>(evals, dt, out + 2*N2, Ttot);

  /* 4. cunmqr on split planes: Cre = Zmat (in place), Cim = 0 */
  k_zeroZ<<<(DN*DN+255)/256,256,0,stream>>>(Cim);
  int Krefl = DN-1;
  for (int i0 = ((Krefl-1)/NB)*NB; i0 >= 0; i0 -= NB){
    int ib = Krefl - i0; if (ib > NB) ib = NB;
    int m = DN-1-i0;
    int row0 = i0+1;
    k_packV<<<((m*ib)+255)/256,256,0,stream>>>(AH, Vp, i0, ib, m);
    k_vhv<<<ib,256,0,stream>>>(Vp, vhv, m, ib);
    k_bldT<<<1,64,0,stream>>>(vhv, tauA+i0, Tm, ib);
    dim3 gct((ib+31)/32,(DN+31)/32);
    k_cgemm_ct_p<<<gct,256,0,stream>>>(Vp, Cre, Cim, G1, row0, m, ib);
    k_cgemm_nn<<<gct,256,0,stream>>>(Tm, NB, G1, NB, G2, NB, ib, DN, ib);
    dim3 gup((m+31)/32,(DN+31)/32);
    k_cupdate_p<<<gup,256,0,stream>>>(Vp, G2, Cre, Cim, row0, m, ib);
  }

  /* 5. V outputs (AH now dead) */
  k_outVre<<<(DN*DN+255)/256,256,0,stream>>>(Cre, out);
  k_outVinv<<<(DN*DN+255)/256,256,0,stream>>>(Cre, out + N2);
}